// Round 15
// baseline (82.524 us; speedup 1.0000x reference)
//
#include <hip/hip_runtime.h>
#include <stdint.h>

typedef __attribute__((ext_vector_type(8))) short bf16x8;
typedef __attribute__((ext_vector_type(4))) float f32x4;
typedef unsigned short u16;

constexpr int NN = 2048, NF = 256;

__device__ inline u16 f2bf(float f) {
  uint32_t u = __builtin_bit_cast(uint32_t, f);
  uint32_t r = (u + 0x7FFFu + ((u >> 16) & 1u)) >> 16;
  return (u16)r;
}
__device__ inline float bf2f(u16 h) {
  uint32_t u = ((uint32_t)h) << 16;
  return __builtin_bit_cast(float, u);
}

__device__ inline void gload_lds16(const void* g, void* l) {
  __builtin_amdgcn_global_load_lds(
      (const __attribute__((address_space(1))) uint32_t*)g,
      (__attribute__((address_space(3))) uint32_t*)l,
      16, 0, 0);
}

// ---- K1: d[row]=rsqrt(1+sum adj[row,:]); tail blocks: Wconv ----------------
__global__ __launch_bounds__(256) void k_rowsum(const float* __restrict__ adj,
                                                float* __restrict__ d,
                                                const float* __restrict__ W,
                                                u16* __restrict__ Wb) {
  if (blockIdx.x >= 16384) {
    int i = (blockIdx.x - 16384) * 256 + threadIdx.x;
    float4 v = ((const float4*)W)[i];
    ushort4 o;
    o.x = f2bf(v.x); o.y = f2bf(v.y); o.z = f2bf(v.z); o.w = f2bf(v.w);
    *(ushort4*)(Wb + (size_t)i * 4) = o;
    return;
  }
  int row = blockIdx.x;
  const float4* p = (const float4*)(adj + (size_t)row * NN);
  float s = 0.f;
#pragma unroll
  for (int c = 0; c < 2; ++c) {
    float4 v = p[threadIdx.x + 256 * c];
    s += v.x + v.y + v.z + v.w;
  }
#pragma unroll
  for (int off = 32; off > 0; off >>= 1) s += __shfl_down(s, off, 64);
  __shared__ float red[4];
  int lane = threadIdx.x & 63, w = threadIdx.x >> 6;
  if (lane == 0) red[w] = s;
  __syncthreads();
  if (threadIdx.x == 0) {
    float t = red[0] + red[1] + red[2] + red[3] + 1.0f;
    d[row] = 1.0f / sqrtf(t);
  }
}

// ---- K2: XpT[b,f,j] = bf16(d_j * X[b,j,f])  (plain transpose) --------------
__global__ __launch_bounds__(256) void k_xprep(const float* __restrict__ X,
                                               const float* __restrict__ d,
                                               u16* __restrict__ XpT) {
  int jt = blockIdx.x, ft = blockIdx.y, b = blockIdx.z;
  int j0 = jt * 64, f0 = ft * 64;
  __shared__ u16 T[64][66];
  int t = threadIdx.x;
#pragma unroll
  for (int s = 0; s < 4; ++s) {
    int q = s * 256 + t;
    int r = q >> 4, c4 = q & 15;
    int j = j0 + r;
    float dv = d[b * NN + j];
    float4 v = *(const float4*)(X + ((size_t)(b * NN + j)) * NF + f0 + c4 * 4);
    T[r][c4 * 4 + 0] = f2bf(v.x * dv);
    T[r][c4 * 4 + 1] = f2bf(v.y * dv);
    T[r][c4 * 4 + 2] = f2bf(v.z * dv);
    T[r][c4 * 4 + 3] = f2bf(v.w * dv);
  }
  __syncthreads();
#pragma unroll
  for (int s = 0; s < 4; ++s) {
    int q = s * 256 + t;
    int fr = q >> 4, c4 = q & 15;
    ushort4 o;
    o.x = T[c4 * 4 + 0][fr]; o.y = T[c4 * 4 + 1][fr];
    o.z = T[c4 * 4 + 2][fr]; o.w = T[c4 * 4 + 3][fr];
    *(ushort4*)(XpT + ((size_t)(b * NF + f0 + fr)) * NN + j0 + c4 * 4) = o;
  }
}

// ---- Fused: H = d_i*(adj@Xp + Xp_i) ; out = relu(H@W^T + bias) -------------
// BM=32, BN=256, BK=32, 256 thr (4 waves 1x4), 512 blocks = 2 blocks/CU.
// Counted vmcnt(9) (clears exactly B(k-2)+A(k-1)); per-step s_barrier.
// B: glds, 4 bufs mod-4, write (k+2)%4 (laggard-read-disjoint).
// A: fp32 adj -> reg float4 (3 sets mod-3) -> cvt -> ds_write, 3 granules.
#define BBASE 8192

#define STEP(KS, M3, W3, B4W, BRD, VMC, IA, WA, IB)                            \
  {                                                                            \
    if (IA) aN[M3] = *(const float4*)(a_gsrc + (size_t)((KS) + 3) * 32);       \
    if (IB) {                                                                  \
      gload_lds16(b_src0 + (size_t)((KS) + 2) * 32,                            \
                  smem + BBASE + (B4W) * 16384 + bwA);                         \
      gload_lds16(b_src1 + (size_t)((KS) + 2) * 32,                            \
                  smem + BBASE + (B4W) * 16384 + 4096 + bwA);                  \
      gload_lds16(b_src2 + (size_t)((KS) + 2) * 32,                            \
                  smem + BBASE + (B4W) * 16384 + 8192 + bwA);                  \
      gload_lds16(b_src3 + (size_t)((KS) + 2) * 32,                            \
                  smem + BBASE + (B4W) * 16384 + 12288 + bwA);                 \
    }                                                                          \
    __builtin_amdgcn_sched_barrier(0);                                         \
    asm volatile("s_waitcnt vmcnt(" VMC ") lgkmcnt(0)" ::: "memory");          \
    __builtin_amdgcn_sched_barrier(0);                                         \
    __builtin_amdgcn_s_barrier();                                              \
    __builtin_amdgcn_sched_barrier(0);                                         \
    const char* Ab = smem + (M3) * 2048;                                       \
    const char* Bb = smem + BBASE + (BRD) * 16384;                             \
    bf16x8 af0 = *(const bf16x8*)(Ab + aoff0);                                 \
    bf16x8 af1 = *(const bf16x8*)(Ab + aoff0 + 1024);                          \
    bf16x8 b0 = *(const bf16x8*)(Bb + boff0);                                  \
    bf16x8 b1 = *(const bf16x8*)(Bb + boff0 + 1024);                           \
    bf16x8 b2 = *(const bf16x8*)(Bb + boff0 + 2048);                           \
    bf16x8 b3 = *(const bf16x8*)(Bb + boff0 + 3072);                           \
    asm volatile("s_waitcnt lgkmcnt(2)" ::: "memory");                         \
    __builtin_amdgcn_sched_barrier(0);                                         \
    __builtin_amdgcn_s_setprio(1);                                             \
    acc[0][0] = __builtin_amdgcn_mfma_f32_16x16x32_bf16(af0, b0, acc[0][0], 0, 0, 0); \
    acc[1][0] = __builtin_amdgcn_mfma_f32_16x16x32_bf16(af1, b0, acc[1][0], 0, 0, 0); \
    acc[0][1] = __builtin_amdgcn_mfma_f32_16x16x32_bf16(af0, b1, acc[0][1], 0, 0, 0); \
    acc[1][1] = __builtin_amdgcn_mfma_f32_16x16x32_bf16(af1, b1, acc[1][1], 0, 0, 0); \
    __builtin_amdgcn_s_setprio(0);                                             \
    __builtin_amdgcn_sched_barrier(0);                                         \
    asm volatile("s_waitcnt lgkmcnt(0)" ::: "memory");                         \
    __builtin_amdgcn_sched_barrier(0);                                         \
    __builtin_amdgcn_s_setprio(1);                                             \
    acc[0][2] = __builtin_amdgcn_mfma_f32_16x16x32_bf16(af0, b2, acc[0][2], 0, 0, 0); \
    acc[1][2] = __builtin_amdgcn_mfma_f32_16x16x32_bf16(af1, b2, acc[1][2], 0, 0, 0); \
    acc[0][3] = __builtin_amdgcn_mfma_f32_16x16x32_bf16(af0, b3, acc[0][3], 0, 0, 0); \
    acc[1][3] = __builtin_amdgcn_mfma_f32_16x16x32_bf16(af1, b3, acc[1][3], 0, 0, 0); \
    __builtin_amdgcn_s_setprio(0);                                             \
    __builtin_amdgcn_sched_barrier(0);                                         \
    if (WA) {                                                                  \
      float4 c0 = aN[W3];                                                      \
      ushort4 pk;                                                              \
      pk.x = f2bf(c0.x); pk.y = f2bf(c0.y);                                    \
      pk.z = f2bf(c0.z); pk.w = f2bf(c0.w);                                    \
      *(ushort4*)(smem + (W3) * 2048 + a_ldst) = pk;                           \
    }                                                                          \
    __builtin_amdgcn_sched_barrier(0);                                         \
  }

__global__ __launch_bounds__(256, 2) void k_fused(
    const float* __restrict__ adj, const u16* __restrict__ XpT,
    const float* __restrict__ dsc, const u16* __restrict__ Wb,
    const float* __restrict__ bias, float* __restrict__ out) {
  int flat = blockIdx.x;
  int b = flat & 7, mt = flat >> 3;  // batch->XCD affinity
  int i0 = mt * 32;

  __shared__ __align__(16) char smem[73728];  // A 3x2K (pad to 8K) | B 4x16K
  u16* Hs = (u16*)smem;                       // epilogue alias [32][264]

  int t = threadIdx.x;
  int lane = t & 63, w = t >> 6;
  int l15 = lane & 15, l4 = lane >> 4;
  int wc = w;

  const float* adjf = adj + ((size_t)b * NN + i0) * NN;
  const u16* XpTb = XpT + (size_t)b * NF * NN;

  // A staging: thread t -> row rA=t>>3 (0..31), kq=t&7 (float4 within 32 k)
  int rA = t >> 3, kq = t & 7;
  int cc = kq >> 1, half = kq & 1;
  const float* a_gsrc = adjf + (size_t)rA * NN + cc * 8 + half * 4;
  int a_ldst = rA * 64 + ((cc ^ ((rA >> 1) & 3)) << 4) + half * 8;

  // B staging (glds, source-swizzled): 4 slots/thread of [256][32] tile
  int q0 = t,            n0 = q0 >> 2, c0 = q0 & 3;
  int q1 = 256 + t,      n1 = q1 >> 2, c1 = q1 & 3;
  int q2 = 512 + t,      n2 = q2 >> 2, c2 = q2 & 3;
  int q3 = 768 + t,      n3 = q3 >> 2, c3 = q3 & 3;
  const u16* b_src0 = XpTb + (size_t)n0 * NN + ((c0 ^ ((n0 >> 1) & 3)) << 3);
  const u16* b_src1 = XpTb + (size_t)n1 * NN + ((c1 ^ ((n1 >> 1) & 3)) << 3);
  const u16* b_src2 = XpTb + (size_t)n2 * NN + ((c2 ^ ((n2 >> 1) & 3)) << 3);
  const u16* b_src3 = XpTb + (size_t)n3 * NN + ((c3 ^ ((n3 >> 1) & 3)) << 3);
  int bwA = w << 10;  // wave-uniform dst base within each 4KB quarter

  // frag read byte offsets
  int swz = (l4 ^ ((l15 >> 1) & 3)) << 4;
  int aoff0 = l15 * 64 + swz;
  int boff0 = (wc * 64 + l15) * 64 + swz;

  f32x4 acc[2][4] = {};
  float4 aN[3];

  // ---- prologue: A data0,data1 -> granules 0,1; B data0,1 -> bufs 0,1;
  //      A data2 -> set 2 ----
  {
    float4 aD0 = *(const float4*)(a_gsrc);
    float4 aD1 = *(const float4*)(a_gsrc + 32);
    __builtin_amdgcn_sched_barrier(0);
    gload_lds16(b_src0, smem + BBASE + bwA);
    gload_lds16(b_src1, smem + BBASE + 4096 + bwA);
    gload_lds16(b_src2, smem + BBASE + 8192 + bwA);
    gload_lds16(b_src3, smem + BBASE + 12288 + bwA);
    gload_lds16(b_src0 + 32, smem + BBASE + 16384 + bwA);
    gload_lds16(b_src1 + 32, smem + BBASE + 16384 + 4096 + bwA);
    gload_lds16(b_src2 + 32, smem + BBASE + 16384 + 8192 + bwA);
    gload_lds16(b_src3 + 32, smem + BBASE + 16384 + 12288 + bwA);
    __builtin_amdgcn_sched_barrier(0);
    aN[2] = *(const float4*)(a_gsrc + 64);
    __builtin_amdgcn_sched_barrier(0);
    asm volatile("s_waitcnt vmcnt(9)" ::: "memory");  // aD0, aD1 done
    __builtin_amdgcn_sched_barrier(0);
    ushort4 pk;
    pk.x = f2bf(aD0.x); pk.y = f2bf(aD0.y);
    pk.z = f2bf(aD0.z); pk.w = f2bf(aD0.w);
    *(ushort4*)(smem + a_ldst) = pk;           // granule 0
    pk.x = f2bf(aD1.x); pk.y = f2bf(aD1.y);
    pk.z = f2bf(aD1.z); pk.w = f2bf(aD1.w);
    *(ushort4*)(smem + 2048 + a_ldst) = pk;    // granule 1
    __builtin_amdgcn_sched_barrier(0);
  }

  // ---- main loop: steps 0..59 (12-step period: mod 3 x mod 4) ----
  for (int sb = 0; sb < 60; sb += 12) {
    STEP(sb + 0,  0, 2, 2, 0, "9", 1, 1, 1)
    STEP(sb + 1,  1, 0, 3, 1, "9", 1, 1, 1)
    STEP(sb + 2,  2, 1, 0, 2, "9", 1, 1, 1)
    STEP(sb + 3,  0, 2, 1, 3, "9", 1, 1, 1)
    STEP(sb + 4,  1, 0, 2, 0, "9", 1, 1, 1)
    STEP(sb + 5,  2, 1, 3, 1, "9", 1, 1, 1)
    STEP(sb + 6,  0, 2, 0, 2, "9", 1, 1, 1)
    STEP(sb + 7,  1, 0, 1, 3, "9", 1, 1, 1)
    STEP(sb + 8,  2, 1, 2, 0, "9", 1, 1, 1)
    STEP(sb + 9,  0, 2, 3, 1, "9", 1, 1, 1)
    STEP(sb + 10, 1, 0, 0, 2, "9", 1, 1, 1)
    STEP(sb + 11, 2, 1, 1, 3, "9", 1, 1, 1)
  }
  // ---- tail: steps 60..63 ----
  STEP(60, 0, 2, 2, 0, "9", 1, 1, 1)   // loads data63->set0; writes data62
  STEP(61, 1, 0, 3, 1, "8", 0, 1, 1)   // writes data63; B data63->buf3
  STEP(62, 2, 1, 0, 2, "4", 0, 0, 0)
  STEP(63, 0, 2, 1, 3, "0", 0, 0, 0)

  __syncthreads();  // drain before Hs aliases staging buffers

  // ---- epilogue 1: H tile -> LDS bf16 [32][264]; +I term from XpT (L2) ----
  const float* db = dsc + b * NN;
#pragma unroll
  for (int mi = 0; mi < 2; ++mi) {
#pragma unroll
    for (int ni = 0; ni < 4; ++ni) {
      int f = wc * 64 + ni * 16 + l15;
      ushort4 xv = *(const ushort4*)(XpTb + (size_t)f * NN + i0 +
                                     mi * 16 + l4 * 4);
#pragma unroll
      for (int qq = 0; qq < 4; ++qq) {
        int il = mi * 16 + l4 * 4 + qq;
        float dv = db[i0 + il];
        float xpv = bf2f(((const u16*)&xv)[qq]);
        float hv = dv * (acc[mi][ni][qq] + xpv);
        Hs[il * 264 + f] = f2bf(hv);
      }
    }
  }
  __syncthreads();

  // ---- epilogue 2: out = relu(H @ W^T + bias), W frags from L2 ----
  f32x4 acc2[2][4] = {};
#pragma unroll
  for (int kk = 0; kk < 256; kk += 32) {
    bf16x8 a2[2], b2[4];
#pragma unroll
    for (int mi = 0; mi < 2; ++mi) {
      int r = mi * 16 + l15;
      a2[mi] = *(const bf16x8*)&Hs[r * 264 + kk + l4 * 8];
    }
#pragma unroll
    for (int ni = 0; ni < 4; ++ni) {
      int o = wc * 64 + ni * 16 + l15;
      b2[ni] = *(const bf16x8*)&Wb[(size_t)o * 256 + kk + l4 * 8];
    }
#pragma unroll
    for (int mi = 0; mi < 2; ++mi)
#pragma unroll
      for (int ni = 0; ni < 4; ++ni)
        acc2[mi][ni] = __builtin_amdgcn_mfma_f32_16x16x32_bf16(a2[mi], b2[ni],
                                                               acc2[mi][ni], 0, 0, 0);
  }

  float* outb = out + ((size_t)b * NN + i0) * NF;
#pragma unroll
  for (int mi = 0; mi < 2; ++mi) {
#pragma unroll
    for (int qq = 0; qq < 4; ++qq) {
      int il = mi * 16 + l4 * 4 + qq;
#pragma unroll
      for (int ni = 0; ni < 4; ++ni) {
        int o = wc * 64 + ni * 16 + l15;
        float v = acc2[mi][ni][qq] + bias[o];
        outb[(size_t)il * NF + o] = fmaxf(v, 0.f);
      }
    }
  }
}

extern "C" void kernel_launch(void* const* d_in, const int* in_sizes, int n_in,
                              void* d_out, int out_size, void* d_ws, size_t ws_size,
                              hipStream_t stream) {
  const float* X    = (const float*)d_in[0];
  const float* adj  = (const float*)d_in[1];
  const float* W    = (const float*)d_in[2];
  const float* bias = (const float*)d_in[3];
  float* out = (float*)d_out;

  char* ws = (char*)d_ws;
  float* dsc = (float*)(ws);                 // 64 KB
  u16*   Wb  = (u16*)(ws + 65536);           // 128 KB
  u16*   XpT = (u16*)(ws + 262144);          // 8 MB

  k_rowsum<<<dim3(16448), dim3(256), 0, stream>>>(adj, dsc, W, Wb);
  k_xprep<<<dim3(32, 4, 8), dim3(256), 0, stream>>>(X, dsc, XpT);
  k_fused<<<dim3(512), dim3(256), 0, stream>>>(adj, XpT, dsc, Wb, bias, out);
}

// Round 16
// 72.203 us; speedup vs baseline: 1.1430x; 1.1430x over previous
//
#include <hip/hip_runtime.h>
#include <stdint.h>

typedef __attribute__((ext_vector_type(8))) short bf16x8;
typedef __attribute__((ext_vector_type(8))) unsigned short u16x8;
typedef __attribute__((ext_vector_type(4))) float f32x4;
typedef unsigned short u16;

constexpr int NN = 2048, NF = 256;

__device__ inline u16 f2bf(float f) {
  uint32_t u = __builtin_bit_cast(uint32_t, f);
  uint32_t r = (u + 0x7FFFu + ((u >> 16) & 1u)) >> 16;
  return (u16)r;
}
__device__ inline float bf2f(u16 h) {
  uint32_t u = ((uint32_t)h) << 16;
  return __builtin_bit_cast(float, u);
}

__device__ inline void gload_lds16(const void* g, void* l) {
  __builtin_amdgcn_global_load_lds(
      (const __attribute__((address_space(1))) uint32_t*)g,
      (__attribute__((address_space(3))) uint32_t*)l,
      16, 0, 0);
}

// ---- K1: d[row]=rsqrt(1+sum adj[row,:]); tail blocks: Wconv ----------------
__global__ __launch_bounds__(256) void k_rowsum(const float* __restrict__ adj,
                                                float* __restrict__ d,
                                                const float* __restrict__ W,
                                                u16* __restrict__ Wb) {
  if (blockIdx.x >= 16384) {
    int i = (blockIdx.x - 16384) * 256 + threadIdx.x;
    float4 v = ((const float4*)W)[i];
    ushort4 o;
    o.x = f2bf(v.x); o.y = f2bf(v.y); o.z = f2bf(v.z); o.w = f2bf(v.w);
    *(ushort4*)(Wb + (size_t)i * 4) = o;
    return;
  }
  int row = blockIdx.x;
  const float4* p = (const float4*)(adj + (size_t)row * NN);
  float s = 0.f;
#pragma unroll
  for (int c = 0; c < 2; ++c) {
    float4 v = p[threadIdx.x + 256 * c];
    s += v.x + v.y + v.z + v.w;
  }
#pragma unroll
  for (int off = 32; off > 0; off >>= 1) s += __shfl_down(s, off, 64);
  __shared__ float red[4];
  int lane = threadIdx.x & 63, w = threadIdx.x >> 6;
  if (lane == 0) red[w] = s;
  __syncthreads();
  if (threadIdx.x == 0) {
    float t = red[0] + red[1] + red[2] + red[3] + 1.0f;
    d[row] = 1.0f / sqrtf(t);
  }
}

// ---- K2: XpT[b,f,j] = bf16(d_j * X[b,j,f])  (plain transpose) --------------
__global__ __launch_bounds__(256) void k_xprep(const float* __restrict__ X,
                                               const float* __restrict__ d,
                                               u16* __restrict__ XpT) {
  int jt = blockIdx.x, ft = blockIdx.y, b = blockIdx.z;
  int j0 = jt * 64, f0 = ft * 64;
  __shared__ u16 T[64][66];
  int t = threadIdx.x;
#pragma unroll
  for (int s = 0; s < 4; ++s) {
    int q = s * 256 + t;
    int r = q >> 4, c4 = q & 15;
    int j = j0 + r;
    float dv = d[b * NN + j];
    float4 v = *(const float4*)(X + ((size_t)(b * NN + j)) * NF + f0 + c4 * 4);
    T[r][c4 * 4 + 0] = f2bf(v.x * dv);
    T[r][c4 * 4 + 1] = f2bf(v.y * dv);
    T[r][c4 * 4 + 2] = f2bf(v.z * dv);
    T[r][c4 * 4 + 3] = f2bf(v.w * dv);
  }
  __syncthreads();
#pragma unroll
  for (int s = 0; s < 4; ++s) {
    int q = s * 256 + t;
    int fr = q >> 4, c4 = q & 15;
    ushort4 o;
    o.x = T[c4 * 4 + 0][fr]; o.y = T[c4 * 4 + 1][fr];
    o.z = T[c4 * 4 + 2][fr]; o.w = T[c4 * 4 + 3][fr];
    *(ushort4*)(XpT + ((size_t)(b * NF + f0 + fr)) * NN + j0 + c4 * 4) = o;
  }
}

// ---- Fused: H = d_i*(adj@Xp + Xp_i) ; out = relu(H@W^T + bias) -------------
// BM=64, BN=256, BK=64 per barrier (32 steps), 512 thr (8 waves 2x4), 1 blk/CU.
// Per-step barrier => skew window = 1 step => 3 bufs for A and B (mod 3):
// read slot S%3, write slot (S+2)%3. B: glds depth-2; A: fp32 regs->cvt->ds.
#define BBASE 24576

#define MFMA8X(A0, A1, B0, B1, B2, B3)                                         \
    __builtin_amdgcn_s_setprio(1);                                             \
    acc[0][0] = __builtin_amdgcn_mfma_f32_16x16x32_bf16(A0, B0, acc[0][0], 0, 0, 0); \
    acc[0][1] = __builtin_amdgcn_mfma_f32_16x16x32_bf16(A0, B1, acc[0][1], 0, 0, 0); \
    acc[0][2] = __builtin_amdgcn_mfma_f32_16x16x32_bf16(A0, B2, acc[0][2], 0, 0, 0); \
    acc[0][3] = __builtin_amdgcn_mfma_f32_16x16x32_bf16(A0, B3, acc[0][3], 0, 0, 0); \
    acc[1][0] = __builtin_amdgcn_mfma_f32_16x16x32_bf16(A1, B0, acc[1][0], 0, 0, 0); \
    acc[1][1] = __builtin_amdgcn_mfma_f32_16x16x32_bf16(A1, B1, acc[1][1], 0, 0, 0); \
    acc[1][2] = __builtin_amdgcn_mfma_f32_16x16x32_bf16(A1, B2, acc[1][2], 0, 0, 0); \
    acc[1][3] = __builtin_amdgcn_mfma_f32_16x16x32_bf16(A1, B3, acc[1][3], 0, 0, 0); \
    __builtin_amdgcn_s_setprio(0);

// Step KS (64 k-cols). R3 = KS%3 (read slot), W3 = (KS+2)%3 (write slot).
#define STEP(KS, R3, W3, VMC, IA, WA, IB)                                      \
  {                                                                            \
    if (IB) {                                                                  \
      gload_lds16(b_src0 + (size_t)((KS) + 2) * 64,                            \
                  smem + BBASE + (W3) * 32768 + bw0);                          \
      gload_lds16(b_src1 + (size_t)((KS) + 2) * 64,                            \
                  smem + BBASE + (W3) * 32768 + bw1);                          \
      gload_lds16(b_src0 + (size_t)((KS) + 2) * 64 + 32,                       \
                  smem + BBASE + (W3) * 32768 + 16384 + bw0);                  \
      gload_lds16(b_src1 + (size_t)((KS) + 2) * 64 + 32,                       \
                  smem + BBASE + (W3) * 32768 + 16384 + bw1);                  \
    }                                                                          \
    if (IA) {                                                                  \
      aN0[R3] = *(const float4*)(a_gsrc + (size_t)((KS) + 3) * 64);            \
      aN1[R3] = *(const float4*)(a_gsrc + (size_t)((KS) + 3) * 64 + 4);        \
    }                                                                          \
    __builtin_amdgcn_sched_barrier(0);                                         \
    asm volatile("s_waitcnt vmcnt(" VMC ") lgkmcnt(0)" ::: "memory");          \
    __builtin_amdgcn_sched_barrier(0);                                         \
    __builtin_amdgcn_s_barrier();                                              \
    __builtin_amdgcn_sched_barrier(0);                                         \
    const char* Ab = smem + (R3) * 8192;                                       \
    const char* Be = smem + BBASE + (R3) * 32768;                              \
    const char* Bo = Be + 16384;                                               \
    bf16x8 a00 = *(const bf16x8*)(Ab + aoff0);                                 \
    bf16x8 a01 = *(const bf16x8*)(Ab + aoff0 + 1024);                          \
    bf16x8 be0 = *(const bf16x8*)(Be + boff0);                                 \
    bf16x8 be1 = *(const bf16x8*)(Be + boff0 + 1024);                          \
    bf16x8 be2 = *(const bf16x8*)(Be + boff0 + 2048);                          \
    bf16x8 be3 = *(const bf16x8*)(Be + boff0 + 3072);                          \
    __builtin_amdgcn_sched_barrier(0);                                         \
    bf16x8 a10 = *(const bf16x8*)(Ab + 4096 + aoff0);                          \
    bf16x8 a11 = *(const bf16x8*)(Ab + 4096 + aoff0 + 1024);                   \
    bf16x8 bo0 = *(const bf16x8*)(Bo + boff0);                                 \
    bf16x8 bo1 = *(const bf16x8*)(Bo + boff0 + 1024);                          \
    bf16x8 bo2 = *(const bf16x8*)(Bo + boff0 + 2048);                          \
    bf16x8 bo3 = *(const bf16x8*)(Bo + boff0 + 3072);                          \
    asm volatile("s_waitcnt lgkmcnt(6)" ::: "memory");                         \
    __builtin_amdgcn_sched_barrier(0);                                         \
    MFMA8X(a00, a01, be0, be1, be2, be3)                                       \
    __builtin_amdgcn_sched_barrier(0);                                         \
    asm volatile("s_waitcnt lgkmcnt(0)" ::: "memory");                         \
    __builtin_amdgcn_sched_barrier(0);                                         \
    MFMA8X(a10, a11, bo0, bo1, bo2, bo3)                                       \
    __builtin_amdgcn_sched_barrier(0);                                         \
    if (WA) {                                                                  \
      float4 c0 = aN0[W3], c1 = aN1[W3];                                       \
      u16x8 pk;                                                                \
      pk[0] = f2bf(c0.x); pk[1] = f2bf(c0.y); pk[2] = f2bf(c0.z);              \
      pk[3] = f2bf(c0.w); pk[4] = f2bf(c1.x); pk[5] = f2bf(c1.y);              \
      pk[6] = f2bf(c1.z); pk[7] = f2bf(c1.w);                                  \
      *(u16x8*)(smem + (W3) * 8192 + a_ldst) = pk;                             \
    }                                                                          \
    __builtin_amdgcn_sched_barrier(0);                                         \
  }

__global__ __launch_bounds__(512, 2) void k_fused(
    const float* __restrict__ adj, const u16* __restrict__ XpT,
    const float* __restrict__ dsc, const u16* __restrict__ Wb,
    const float* __restrict__ bias, float* __restrict__ out) {
  int flat = blockIdx.x;
  int b = flat & 7, mt = flat >> 3;  // batch->XCD affinity
  int i0 = mt * 64;

  __shared__ __align__(16) char smem[122880];  // A 3x8K | B 3x32K ; Hs aliases
  u16* Hs = (u16*)smem;

  int t = threadIdx.x;
  int lane = t & 63, w = t >> 6;
  int l15 = lane & 15, l4 = lane >> 4;
  int wr = w >> 2, wc = w & 3;

  const float* adjf = adj + ((size_t)b * NN + i0) * NN;
  const u16* XpTb = XpT + (size_t)b * NF * NN;

  // A staging: thread t -> row rA=t>>3, 8-float chunk kc=t&7 within 64-k step
  int rA = t >> 3, kc = t & 7;
  const float* a_gsrc = adjf + (size_t)rA * NN + kc * 8;
  int a_ldst = (kc >> 2) * 4096 + rA * 64 + (((kc & 3) ^ ((rA >> 1) & 3)) << 4);

  // B staging (glds, source-swizzled): slots t and t+512 of [256][32] per half
  int n0s = t >> 2, c0s = t & 3;
  const u16* b_src0 = XpTb + (size_t)n0s * NN + ((c0s ^ ((n0s >> 1) & 3)) << 3);
  int s1 = 512 + t;
  int n1s = s1 >> 2, c1s = s1 & 3;
  const u16* b_src1 = XpTb + (size_t)n1s * NN + ((c1s ^ ((n1s >> 1) & 3)) << 3);
  int bw0 = w << 10;
  int bw1 = 8192 + (w << 10);

  // frag read byte offsets
  int swz = (l4 ^ ((l15 >> 1) & 3)) << 4;
  int aoff0 = wr * 2048 + l15 * 64 + swz;
  int boff0 = (wc * 64 + l15) * 64 + swz;

  f32x4 acc[2][4] = {};
  float4 aN0[3], aN1[3];

  // ---- prologue: A steps 0,1 -> granules 0,1; B steps 0,1 -> bufs 0,1;
  //      A step 2 -> reg set 2 ----
  {
    float4 p0a = *(const float4*)(a_gsrc);
    float4 p0b = *(const float4*)(a_gsrc + 4);
    float4 p1a = *(const float4*)(a_gsrc + 64);
    float4 p1b = *(const float4*)(a_gsrc + 68);
    __builtin_amdgcn_sched_barrier(0);
    gload_lds16(b_src0, smem + BBASE + bw0);
    gload_lds16(b_src1, smem + BBASE + bw1);
    gload_lds16(b_src0 + 32, smem + BBASE + 16384 + bw0);
    gload_lds16(b_src1 + 32, smem + BBASE + 16384 + bw1);
    gload_lds16(b_src0 + 64, smem + BBASE + 32768 + bw0);
    gload_lds16(b_src1 + 64, smem + BBASE + 32768 + bw1);
    gload_lds16(b_src0 + 96, smem + BBASE + 32768 + 16384 + bw0);
    gload_lds16(b_src1 + 96, smem + BBASE + 32768 + 16384 + bw1);
    __builtin_amdgcn_sched_barrier(0);
    aN0[2] = *(const float4*)(a_gsrc + 128);  // step 2 -> set 2
    aN1[2] = *(const float4*)(a_gsrc + 132);
    __builtin_amdgcn_sched_barrier(0);
    u16x8 pk;
    pk[0] = f2bf(p0a.x); pk[1] = f2bf(p0a.y); pk[2] = f2bf(p0a.z);
    pk[3] = f2bf(p0a.w); pk[4] = f2bf(p0b.x); pk[5] = f2bf(p0b.y);
    pk[6] = f2bf(p0b.z); pk[7] = f2bf(p0b.w);
    *(u16x8*)(smem + a_ldst) = pk;            // granule 0
    pk[0] = f2bf(p1a.x); pk[1] = f2bf(p1a.y); pk[2] = f2bf(p1a.z);
    pk[3] = f2bf(p1a.w); pk[4] = f2bf(p1b.x); pk[5] = f2bf(p1b.y);
    pk[6] = f2bf(p1b.z); pk[7] = f2bf(p1b.w);
    *(u16x8*)(smem + 8192 + a_ldst) = pk;     // granule 1
    __builtin_amdgcn_sched_barrier(0);
  }

  // ---- steps 0,1 peeled (prologue-adjusted vmcnt) ----
  STEP(0, 0, 2, "10", 1, 1, 1)
  STEP(1, 1, 0, "12", 1, 1, 1)
  // ---- main loop: steps 2..25 (8 x 3, period-3 literals) ----
  for (int sb = 2; sb <= 23; sb += 3) {
    STEP(sb + 0, 2, 1, "12", 1, 1, 1)
    STEP(sb + 1, 0, 2, "12", 1, 1, 1)
    STEP(sb + 2, 1, 0, "12", 1, 1, 1)
  }
  // ---- tail: steps 26..31 ----
  STEP(26, 2, 1, "12", 1, 1, 1)
  STEP(27, 0, 2, "12", 1, 1, 1)
  STEP(28, 1, 0, "12", 1, 1, 1)
  STEP(29, 2, 1, "12", 0, 1, 1)
  STEP(30, 0, 2, "4", 0, 0, 0)
  STEP(31, 1, 0, "0", 0, 0, 0)

  __syncthreads();  // drain all before Hs aliases staging buffers

  // ---- epilogue 1: H -> LDS bf16 [64][264]; +I term from XpT (L2) ----
  const float* db = dsc + b * NN;
#pragma unroll
  for (int mi = 0; mi < 2; ++mi) {
#pragma unroll
    for (int ni = 0; ni < 4; ++ni) {
      int f = wc * 64 + ni * 16 + l15;
      ushort4 xv = *(const ushort4*)(XpTb + (size_t)f * NN + i0 +
                                     wr * 32 + mi * 16 + l4 * 4);
#pragma unroll
      for (int qq = 0; qq < 4; ++qq) {
        int il = wr * 32 + mi * 16 + l4 * 4 + qq;
        float dv = db[i0 + il];
        float xpv = bf2f(((const u16*)&xv)[qq]);
        float hv = dv * (acc[mi][ni][qq] + xpv);
        Hs[il * 264 + f] = f2bf(hv);
      }
    }
  }
  __syncthreads();

  // ---- epilogue 2: out = relu(H @ W^T + bias), W frags from L2 ----
  f32x4 acc2[2][4] = {};
#pragma unroll
  for (int kk = 0; kk < 256; kk += 32) {
    bf16x8 a2[2], b2[4];
#pragma unroll
    for (int mi = 0; mi < 2; ++mi) {
      int r = wr * 32 + mi * 16 + l15;
      a2[mi] = *(const bf16x8*)&Hs[r * 264 + kk + l4 * 8];
    }
#pragma unroll
    for (int ni = 0; ni < 4; ++ni) {
      int o = wc * 64 + ni * 16 + l15;
      b2[ni] = *(const bf16x8*)&Wb[(size_t)o * 256 + kk + l4 * 8];
    }
#pragma unroll
    for (int mi = 0; mi < 2; ++mi)
#pragma unroll
      for (int ni = 0; ni < 4; ++ni)
        acc2[mi][ni] = __builtin_amdgcn_mfma_f32_16x16x32_bf16(a2[mi], b2[ni],
                                                               acc2[mi][ni], 0, 0, 0);
  }

  float* outb = out + ((size_t)b * NN + i0) * NF;
#pragma unroll
  for (int mi = 0; mi < 2; ++mi) {
#pragma unroll
    for (int qq = 0; qq < 4; ++qq) {
      int il = wr * 32 + mi * 16 + l4 * 4 + qq;
#pragma unroll
      for (int ni = 0; ni < 4; ++ni) {
        int o = wc * 64 + ni * 16 + l15;
        float v = acc2[mi][ni][qq] + bias[o];
        outb[(size_t)il * NF + o] = fmaxf(v, 0.f);
      }
    }
  }
}

extern "C" void kernel_launch(void* const* d_in, const int* in_sizes, int n_in,
                              void* d_out, int out_size, void* d_ws, size_t ws_size,
                              hipStream_t stream) {
  const float* X    = (const float*)d_in[0];
  const float* adj  = (const float*)d_in[1];
  const float* W    = (const float*)d_in[2];
  const float* bias = (const float*)d_in[3];
  float* out = (float*)d_out;

  char* ws = (char*)d_ws;
  float* dsc = (float*)(ws);                 // 64 KB
  u16*   Wb  = (u16*)(ws + 65536);           // 128 KB
  u16*   XpT = (u16*)(ws + 262144);          // 8 MB

  k_rowsum<<<dim3(16448), dim3(256), 0, stream>>>(adj, dsc, W, Wb);
  k_xprep<<<dim3(32, 4, 8), dim3(256), 0, stream>>>(X, dsc, XpT);
  k_fused<<<dim3(256), dim3(512), 0, stream>>>(adj, XpT, dsc, Wb, bias, out);
}